// Round 3
// baseline (504.460 us; speedup 1.0000x reference)
//
#include <hip/hip_runtime.h>
#include <hip/hip_bf16.h>

// CARAFE fused, ZERO-workspace, runtime-dtype-adaptive.
// x(4,256,64,64), Wc(64,256), bc(64), We(100,64,3,3), be(100)
//   -> out(4,256,128,128), SF=2 K=5 G=1 CC=64 EK=3.
// Input/output dtype (bf16 vs fp32) detected per block from x's bit patterns:
// fp32 data reinterpreted as bf16 contains exponent-all-ones (NaN) patterns
// with ~0.4% density; genuine bf16 N(0,1) data contains none.

#define CIN 256
#define CCH 64
#define HWv 4096

// divergent-safe load
template <typename T>
__device__ __forceinline__ float ldv(const T* __restrict__ p, int i) {
    if constexpr (sizeof(T) == 2) return __bfloat162float(p[i]);
    else return p[i];
}

// wave-uniform load (index must be uniform) -> compiler can scalarize.
// bf16 path loads the containing dword and extracts, so it stays >=32-bit.
template <typename T>
__device__ __forceinline__ float lds_uni(const T* __restrict__ p, int i) {
    if constexpr (sizeof(T) == 2) {
        const unsigned* p32 = (const unsigned*)p;
        unsigned u = p32[i >> 1];
        return __uint_as_float((i & 1) ? (u & 0xFFFF0000u) : (u << 16));
    } else {
        return ((const float*)p)[i];
    }
}

template <typename T>
__device__ void carafe_body(const T* __restrict__ x, const T* __restrict__ Wc,
                            const T* __restrict__ bc, const T* __restrict__ We,
                            const T* __restrict__ be, T* __restrict__ out,
                            float* __restrict__ compS, int n, int tile) {
    const int ty0 = (tile >> 3) * 8, tx0 = (tile & 7) * 8;
    const T* xn = x + (size_t)n * CIN * HWv;

    // ---- phase A: channel compressor (1x1 conv, 256->64) into LDS ----
    // thread -> (halo pixel pa in 10x10, cc-half ga); 128 px-slots x 2 halves.
    {
        int pa = threadIdx.x & 127;
        int ga = __builtin_amdgcn_readfirstlane(threadIdx.x >> 7);  // 0/1, wave-uniform
        bool act = pa < 100;
        int ah = ty0 + pa / 10 - 1, aw = tx0 + pa % 10 - 1;
        bool inb = act && ah >= 0 && ah < 64 && aw >= 0 && aw < 64;
        int xoff = ah * 64 + aw;
        float acc[32];
#pragma unroll
        for (int i = 0; i < 32; ++i) acc[i] = 0.f;
        for (int c = 0; c < CIN; c += 2) {
            float xv0 = inb ? ldv(xn, c * HWv + xoff) : 0.f;
            float xv1 = inb ? ldv(xn, (c + 1) * HWv + xoff) : 0.f;
#pragma unroll
            for (int i = 0; i < 32; ++i) {
                int cc = ga * 32 + i;
                acc[i] += xv0 * lds_uni(Wc, cc * 256 + c);      // uniform -> s_load
                acc[i] += xv1 * lds_uni(Wc, cc * 256 + c + 1);  // same dword, CSE'd
            }
        }
        if (act) {
#pragma unroll
            for (int i = 0; i < 32; ++i) {
                int cc = ga * 32 + i;
                // in-image: conv + bias; outside image: encoder sees zero padding
                compS[cc * 101 + pa] = inb ? acc[i] + lds_uni(bc, cc) : 0.f;
            }
        }
    }
    __syncthreads();

    // ---- phase B: content encoder (3x3 conv, 64->100) + softmax(25) ----
    // thread -> (pixel px in 8x8 tile, ij via wave). Owns full 25-k group.
    int px = threadIdx.x & 63;
    int ij = __builtin_amdgcn_readfirstlane(threadIdx.x >> 6);  // 0..3, wave-uniform
    int py = px >> 3, pxx = px & 7;
    int h = ty0 + py, w = tx0 + pxx;

    float m[25];
#pragma unroll
    for (int k = 0; k < 25; ++k) m[k] = lds_uni(be, 4 * k + ij);

    for (int cc = 0; cc < CCH; ++cc) {
        float cv[9];
#pragma unroll
        for (int dy = 0; dy < 3; ++dy)
#pragma unroll
            for (int dx = 0; dx < 3; ++dx)
                cv[dy * 3 + dx] = compS[cc * 101 + (py + dy) * 10 + (pxx + dx)];
        int base = cc * 9;
#pragma unroll
        for (int k = 0; k < 25; ++k) {
            int ebase = (4 * k + ij) * 576 + base;  // uniform; +qb contiguous (K$ lines)
            float s = 0.f;
#pragma unroll
            for (int qb = 0; qb < 9; ++qb)
                s += cv[qb] * lds_uni(We, ebase + qb);
            m[k] += s;
        }
    }

    float mx = m[0];
#pragma unroll
    for (int k = 1; k < 25; ++k) mx = fmaxf(mx, m[k]);
    float ssum = 0.f;
#pragma unroll
    for (int k = 0; k < 25; ++k) { m[k] = __expf(m[k] - mx); ssum += m[k]; }
    float inv = 1.f / ssum;
#pragma unroll
    for (int k = 0; k < 25; ++k) m[k] *= inv;

    // ---- phase C: reassembly, out[n][c][2h+i][2w+j] for all 256 c ----
    int offs[25];
    unsigned vm = 0;
#pragma unroll
    for (int t = 0; t < 25; ++t) {
        int hh = h + t / 5 - 2, ww = w + t % 5 - 2;
        bool v = hh >= 0 && hh < 64 && ww >= 0 && ww < 64;
        offs[t] = v ? hh * 64 + ww : 0;
        if (v) vm |= 1u << t;
    }
    size_t outp = ((size_t)n * CIN * 128 + (2 * h + (ij >> 1))) * 128 + (2 * w + (ij & 1));
    for (int c = 0; c < CIN; ++c) {
        const T* xc = xn + (size_t)c * HWv;
        float sum = 0.f;
#pragma unroll
        for (int t = 0; t < 25; ++t) {
            float xv = ((vm >> t) & 1u) ? ldv(xc, offs[t]) : 0.f;
            sum += xv * m[t];
        }
        if constexpr (sizeof(T) == 2)
            out[outp + (size_t)c * 16384] = __float2bfloat16(sum);
        else
            out[outp + (size_t)c * 16384] = sum;
    }
}

__global__ __launch_bounds__(256) void k_carafe(const void* __restrict__ x,
                                                const void* __restrict__ Wc,
                                                const void* __restrict__ bc,
                                                const void* __restrict__ We,
                                                const void* __restrict__ be,
                                                void* __restrict__ out) {
    __shared__ float compS[CCH * 101];  // 25.9 KB
    __shared__ int sflag;
    if (threadIdx.x == 0) sflag = 0;
    __syncthreads();

    // dtype probe: scan first 16384 ushorts of x (in-bounds for both dtypes)
    {
        const ushort4* xq = (const ushort4*)x;
        int bad = 0;
        for (int i = threadIdx.x; i < 4096; i += 256) {
            ushort4 q = xq[i];
            bad |= ((q.x & 0x7F80) == 0x7F80) | ((q.y & 0x7F80) == 0x7F80) |
                   ((q.z & 0x7F80) == 0x7F80) | ((q.w & 0x7F80) == 0x7F80);
        }
        if (bad) atomicOr(&sflag, 1);
    }
    __syncthreads();
    int f32 = sflag;

    int n = blockIdx.x >> 6, tile = blockIdx.x & 63;
    if (f32)
        carafe_body<float>((const float*)x, (const float*)Wc, (const float*)bc,
                           (const float*)We, (const float*)be, (float*)out,
                           compS, n, tile);
    else
        carafe_body<__hip_bfloat16>((const __hip_bfloat16*)x, (const __hip_bfloat16*)Wc,
                                    (const __hip_bfloat16*)bc, (const __hip_bfloat16*)We,
                                    (const __hip_bfloat16*)be, (__hip_bfloat16*)out,
                                    compS, n, tile);
}

extern "C" void kernel_launch(void* const* d_in, const int* in_sizes, int n_in,
                              void* d_out, int out_size, void* d_ws, size_t ws_size,
                              hipStream_t stream) {
    hipLaunchKernelGGL(k_carafe, dim3(256), dim3(256), 0, stream,
                       d_in[0], d_in[1], d_in[2], d_in[3], d_in[4], d_out);
}

// Round 4
// 201.122 us; speedup vs baseline: 2.5082x; 2.5082x over previous
//
#include <hip/hip_runtime.h>
#include <hip/hip_bf16.h>

// CARAFE fp32 pipeline. x(4,256,64,64), Wc(64,256), bc(64), We(100,64,3,3),
// be(100) -> out(4,256,128,128). SF=2 K=5 G=1 CC=64 EK=3. All I/O fp32
// (confirmed round 3: WRITE_SIZE ~= 67 MB fp32 out; round-1 NaN = fp32 read as bf16).
//
// ws layout (fp32 elements):
//   comp  [4][64][66*66]   zero-padded halo   @ 0        (1,115,136)
//   Wr    [ij4][cc64][q9][k pad28]            @ 1,115,136  (64,512)
//   logit [16384 px][100]  e = 4k+ij          @ 1,179,648  (1,638,400)
// total 2,818,048 floats = 11,272,192 B. Host-gated on ws_size; fallback =
// round-3 fused kernel (known-passing) if ws too small.

#define COMP_F 0
#define WR_F   1115136
#define LOG_F  1179648
#define WS_NEED 11272192ull
#define CSTR 4356  // 66*66 comp per-channel stride

// ---------------- K0: We(100,576) -> Wr[ij][cc][q][k28] ----------------
__global__ void k0_wr(const float* __restrict__ We, float* __restrict__ ws) {
    int tid = blockIdx.x * blockDim.x + threadIdx.x;
    if (tid >= 4 * 64 * 9 * 25) return;
    int k  = tid % 25;
    int q  = (tid / 25) % 9;
    int cc = (tid / 225) % 64;
    int ij = tid / 14400;
    ws[WR_F + (((size_t)(ij * 64 + cc) * 9) + q) * 28 + k] =
        We[(size_t)(4 * k + ij) * 576 + cc * 9 + q];
}

// ---------------- K1: 1x1 compressor 256->64, padded comp out ----------
// grid 2048 x 64thr: b = ccg*256 + pw  (same-pixel siblings share XCD L2).
__global__ __launch_bounds__(64) void k1_comp(const float* __restrict__ x,
                                              const float* __restrict__ Wc,
                                              const float* __restrict__ bc,
                                              float* __restrict__ ws) {
    int b   = blockIdx.x;
    int pw  = b & 255;
    int ccg = b >> 8;          // 0..7, wave-uniform
    int n = pw >> 6, h = pw & 63, w = threadIdx.x;
    int cc0 = ccg * 8;

    float acc[8];
#pragma unroll
    for (int u = 0; u < 8; ++u) acc[u] = 0.f;

    const float* xp = x + (size_t)n * 256 * 4096 + h * 64 + w;
#pragma unroll 4
    for (int c = 0; c < 256; ++c) {
        float xv = xp[(size_t)c * 4096];
#pragma unroll
        for (int u = 0; u < 8; ++u)
            acc[u] += xv * Wc[(cc0 + u) * 256 + c];  // uniform -> s_load
    }

    float* compb = ws + COMP_F + (size_t)(n * 64 + cc0) * CSTR;
#pragma unroll
    for (int u = 0; u < 8; ++u) {
        float* cb_ = compb + (size_t)u * CSTR;
        cb_[(h + 1) * 66 + (w + 1)] = acc[u] + bc[cc0 + u];
        // zero halo border (pad=1 of the 3x3 conv)
        if (w < 2) cb_[(h + 1) * 66 + (w ? 65 : 0)] = 0.f;
        if (h == 0)  { cb_[w] = 0.f;           if (w < 2) cb_[64 + w] = 0.f; }
        if (h == 63) { cb_[65 * 66 + w] = 0.f; if (w < 2) cb_[65 * 66 + 64 + w] = 0.f; }
    }
}

// ---------------- K2: 3x3 encoder -> raw logits (k-split, LDS weights) --
template <int K0, int KR>
__device__ void enc_body(const float* __restrict__ compn, const float* __restrict__ wrij,
                         const float* __restrict__ be, float* __restrict__ logits,
                         float* __restrict__ WsL, int n, int th, int tw, int ij) {
    int lane = threadIdx.x;
    int py = lane >> 3, pxx = lane & 7;
    int h = th * 8 + py, w = tw * 8 + pxx;

    float acc[KR];
#pragma unroll
    for (int kk = 0; kk < KR; ++kk) acc[kk] = be[4 * (K0 + kk) + ij];

    for (int cb = 0; cb < 64; cb += 16) {
        // stage 16cc x 9q x KR weights into LDS (rows padded to 16)
        for (int p = lane; p < 144; p += 64) {
            int c_ = p / 9, q = p % 9;
            const float* src = wrij + (size_t)(cb + c_) * 252 + q * 28 + K0;
            float* dst = WsL + p * 16;
#pragma unroll
            for (int kk = 0; kk < KR; ++kk) dst[kk] = src[kk];
        }
        __syncthreads();
#pragma unroll 2
        for (int c_ = 0; c_ < 16; ++c_) {
            const float* cp = compn + (size_t)(cb + c_) * CSTR + h * 66 + w;
            float cv[9];
#pragma unroll
            for (int dy = 0; dy < 3; ++dy)
#pragma unroll
                for (int dx = 0; dx < 3; ++dx)
                    cv[dy * 3 + dx] = cp[dy * 66 + dx];  // padded: no bounds checks
#pragma unroll
            for (int q = 0; q < 9; ++q) {
                float v = cv[q];
                const float* row = WsL + (c_ * 9 + q) * 16;
#pragma unroll
                for (int kk = 0; kk < KR; ++kk) acc[kk] += v * row[kk];
            }
        }
        __syncthreads();
    }

    float* lp = logits + (size_t)(n * 4096 + h * 64 + w) * 100 + ij;
#pragma unroll
    for (int kk = 0; kk < KR; ++kk) lp[4 * (K0 + kk)] = acc[kk];
}

// grid 2048 x 64thr: b = kh*1024 + ij*256 + tile (siblings share XCD L2).
__global__ __launch_bounds__(64) void k2_enc(const float* __restrict__ be,
                                             float* __restrict__ ws) {
    __shared__ float WsL[144 * 16];  // 9.2 KB
    int b    = blockIdx.x;
    int tile = b & 255;
    int ij   = (b >> 8) & 3;
    int kh   = b >> 10;
    int n = tile >> 6, th = (tile >> 3) & 7, tw = tile & 7;

    const float* compn = ws + COMP_F + (size_t)n * 64 * CSTR;
    const float* wrij  = ws + WR_F + (size_t)ij * 64 * 252;
    float* logits = ws + LOG_F;
    if (kh == 0) enc_body<0, 13>(compn, wrij, be, logits, WsL, n, th, tw, ij);
    else         enc_body<13, 12>(compn, wrij, be, logits, WsL, n, th, tw, ij);
}

// ---------------- K3: softmax (in-reg) + reassembly ---------------------
// grid 1024 x 256thr: b = cchunk*64 + tile. 16x16 px tile, 16-c chunk.
__global__ __launch_bounds__(256) void k3_out(const float* __restrict__ x,
                                              const float* __restrict__ ws,
                                              float* __restrict__ out) {
    __shared__ float xt[16 * 400];  // 20x20 halo x 16c, 25.6 KB
    int b      = blockIdx.x;
    int tile   = b & 63;
    int cchunk = b >> 6;
    int n = tile >> 4, ty0 = ((tile >> 2) & 3) * 16, tx0 = (tile & 3) * 16;
    int c0 = cchunk * 16;

    const float* xn = x + (size_t)(n * 256 + c0) * 4096;
    for (int e = threadIdx.x; e < 16 * 400; e += 256) {
        int c = e / 400, r = (e % 400) / 20, q = e % 20;
        int hh = ty0 + r - 2, ww = tx0 + q - 2;
        float v = 0.f;
        if (hh >= 0 && hh < 64 && ww >= 0 && ww < 64) v = xn[(size_t)c * 4096 + hh * 64 + ww];
        xt[e] = v;
    }

    int py = threadIdx.x >> 4, pxx = threadIdx.x & 15;
    int h = ty0 + py, w = tx0 + pxx;
    const float* lp = ws + LOG_F + (size_t)(n * 4096 + h * 64 + w) * 100;
    float4 mk[25];
#pragma unroll
    for (int t = 0; t < 25; ++t) mk[t] = ((const float4*)lp)[t];

    // softmax over the 25 taps, per ij component (recomputed per c-chunk: free)
    float4 mx = mk[0];
#pragma unroll
    for (int t = 1; t < 25; ++t) {
        mx.x = fmaxf(mx.x, mk[t].x); mx.y = fmaxf(mx.y, mk[t].y);
        mx.z = fmaxf(mx.z, mk[t].z); mx.w = fmaxf(mx.w, mk[t].w);
    }
    float4 sm = {0.f, 0.f, 0.f, 0.f};
#pragma unroll
    for (int t = 0; t < 25; ++t) {
        mk[t].x = __expf(mk[t].x - mx.x); sm.x += mk[t].x;
        mk[t].y = __expf(mk[t].y - mx.y); sm.y += mk[t].y;
        mk[t].z = __expf(mk[t].z - mx.z); sm.z += mk[t].z;
        mk[t].w = __expf(mk[t].w - mx.w); sm.w += mk[t].w;
    }
    float4 iv = {1.f / sm.x, 1.f / sm.y, 1.f / sm.z, 1.f / sm.w};
#pragma unroll
    for (int t = 0; t < 25; ++t) {
        mk[t].x *= iv.x; mk[t].y *= iv.y; mk[t].z *= iv.z; mk[t].w *= iv.w;
    }
    __syncthreads();

    for (int c = 0; c < 16; ++c) {
        const float* xc = xt + c * 400 + py * 20 + pxx;
        float a0 = 0.f, a1 = 0.f, a2 = 0.f, a3 = 0.f;
#pragma unroll
        for (int t = 0; t < 25; ++t) {
            float v = xc[(t / 5) * 20 + (t % 5)];
            a0 += v * mk[t].x; a1 += v * mk[t].y;
            a2 += v * mk[t].z; a3 += v * mk[t].w;
        }
        size_t ob = (((size_t)(n * 256 + c0 + c) * 128) + 2 * h) * 128 + 2 * w;
        float2 r0 = {a0, a1}, r1 = {a2, a3};
        *(float2*)(out + ob)       = r0;
        *(float2*)(out + ob + 128) = r1;
    }
}

// ---------------- Fallback: round-3 fused kernel, fp32-only -------------
__global__ __launch_bounds__(256) void k_fused(const float* __restrict__ x,
                                               const float* __restrict__ Wc,
                                               const float* __restrict__ bc,
                                               const float* __restrict__ We,
                                               const float* __restrict__ be,
                                               float* __restrict__ out) {
    __shared__ float compS[64 * 101];
    int n = blockIdx.x >> 6, tile = blockIdx.x & 63;
    int ty0 = (tile >> 3) * 8, tx0 = (tile & 7) * 8;
    const float* xn = x + (size_t)n * 256 * 4096;
    {
        int pa = threadIdx.x & 127;
        int ga = __builtin_amdgcn_readfirstlane(threadIdx.x >> 7);
        bool act = pa < 100;
        int ah = ty0 + pa / 10 - 1, aw = tx0 + pa % 10 - 1;
        bool inb = act && ah >= 0 && ah < 64 && aw >= 0 && aw < 64;
        int xoff = ah * 64 + aw;
        float acc[32];
#pragma unroll
        for (int i = 0; i < 32; ++i) acc[i] = 0.f;
        for (int c = 0; c < 256; ++c) {
            float xv = inb ? xn[(size_t)c * 4096 + xoff] : 0.f;
#pragma unroll
            for (int i = 0; i < 32; ++i) acc[i] += xv * Wc[(ga * 32 + i) * 256 + c];
        }
        if (act)
#pragma unroll
            for (int i = 0; i < 32; ++i) {
                int cc = ga * 32 + i;
                compS[cc * 101 + pa] = inb ? acc[i] + bc[cc] : 0.f;
            }
    }
    __syncthreads();
    int px = threadIdx.x & 63;
    int ij = __builtin_amdgcn_readfirstlane(threadIdx.x >> 6);
    int py = px >> 3, pxx = px & 7;
    int h = ty0 + py, w = tx0 + pxx;
    float m[25];
#pragma unroll
    for (int k = 0; k < 25; ++k) m[k] = be[4 * k + ij];
    for (int cc = 0; cc < 64; ++cc) {
        float cv[9];
#pragma unroll
        for (int dy = 0; dy < 3; ++dy)
#pragma unroll
            for (int dx = 0; dx < 3; ++dx)
                cv[dy * 3 + dx] = compS[cc * 101 + (py + dy) * 10 + (pxx + dx)];
        int base = cc * 9;
#pragma unroll
        for (int k = 0; k < 25; ++k) {
            int eb = (4 * k + ij) * 576 + base;
            float s = 0.f;
#pragma unroll
            for (int qb = 0; qb < 9; ++qb) s += cv[qb] * We[eb + qb];
            m[k] += s;
        }
    }
    float mxv = m[0];
#pragma unroll
    for (int k = 1; k < 25; ++k) mxv = fmaxf(mxv, m[k]);
    float ss = 0.f;
#pragma unroll
    for (int k = 0; k < 25; ++k) { m[k] = __expf(m[k] - mxv); ss += m[k]; }
    float inv = 1.f / ss;
#pragma unroll
    for (int k = 0; k < 25; ++k) m[k] *= inv;
    int offs[25];
    unsigned vm = 0;
#pragma unroll
    for (int t = 0; t < 25; ++t) {
        int hh = h + t / 5 - 2, ww = w + t % 5 - 2;
        bool v = hh >= 0 && hh < 64 && ww >= 0 && ww < 64;
        offs[t] = v ? hh * 64 + ww : 0;
        if (v) vm |= 1u << t;
    }
    size_t outp = ((size_t)n * 256 * 128 + (2 * h + (ij >> 1))) * 128 + (2 * w + (ij & 1));
    for (int c = 0; c < 256; ++c) {
        const float* xc = xn + (size_t)c * 4096;
        float sum = 0.f;
#pragma unroll
        for (int t = 0; t < 25; ++t) {
            float v = ((vm >> t) & 1u) ? xc[offs[t]] : 0.f;
            sum += v * m[t];
        }
        out[outp + (size_t)c * 16384] = sum;
    }
}

extern "C" void kernel_launch(void* const* d_in, const int* in_sizes, int n_in,
                              void* d_out, int out_size, void* d_ws, size_t ws_size,
                              hipStream_t stream) {
    const float* x  = (const float*)d_in[0];
    const float* Wc = (const float*)d_in[1];
    const float* bc = (const float*)d_in[2];
    const float* We = (const float*)d_in[3];
    const float* be = (const float*)d_in[4];
    float* out = (float*)d_out;

    if (ws_size >= WS_NEED && d_ws != nullptr) {
        float* ws = (float*)d_ws;
        hipLaunchKernelGGL(k0_wr,   dim3(225),  dim3(256), 0, stream, We, ws);
        hipLaunchKernelGGL(k1_comp, dim3(2048), dim3(64),  0, stream, x, Wc, bc, ws);
        hipLaunchKernelGGL(k2_enc,  dim3(2048), dim3(64),  0, stream, be, ws);
        hipLaunchKernelGGL(k3_out,  dim3(1024), dim3(256), 0, stream, x, ws, out);
    } else {
        hipLaunchKernelGGL(k_fused, dim3(256),  dim3(256), 0, stream,
                           x, Wc, bc, We, be, out);
    }
}